// Round 1
// baseline (1388.157 us; speedup 1.0000x reference)
//
#include <hip/hip_runtime.h>
#include <hip/hip_bf16.h>

#define Bsz 32
#define Ssz 128
#define Tsz 64
#define TD  63           // decoder steps
#define NSTEP 191        // Ssz + TD
#define Esz 128
#define Hsz 256
#define G4  1024         // 4*H
#define Vsz 32000
#define NB  16           // recurrence blocks

typedef __attribute__((ext_vector_type(8))) short short8;
typedef __attribute__((ext_vector_type(4))) float f32x4;

__device__ __forceinline__ unsigned short f2bf(float f) {
    union { float f; unsigned u; } v; v.f = f;
    unsigned u = v.u;
    unsigned r = u + 0x7FFFu + ((u >> 16) & 1u);   // RNE
    return (unsigned short)(r >> 16);
}

__device__ __forceinline__ float sigm(float x) {
    return 1.f / (1.f + __expf(-x));
}

// ---------------------------------------------------------------------------
// K0: convert Wfc fp32 -> bf16 in workspace
// ---------------------------------------------------------------------------
__global__ void k_cvt(const float* __restrict__ src, unsigned short* __restrict__ dst, long n) {
    long i = (long)blockIdx.x * blockDim.x + threadIdx.x;
    long base = i * 8;
    if (base >= n) return;
    float4 f0 = ((const float4*)(src + base))[0];
    float4 f1 = ((const float4*)(src + base))[1];
    union { unsigned short u[8]; uint4 v; } r;
    r.u[0] = f2bf(f0.x); r.u[1] = f2bf(f0.y); r.u[2] = f2bf(f0.z); r.u[3] = f2bf(f0.w);
    r.u[4] = f2bf(f1.x); r.u[5] = f2bf(f1.y); r.u[6] = f2bf(f1.z); r.u[7] = f2bf(f1.w);
    *(uint4*)(dst + base) = r.v;
}

// ---------------------------------------------------------------------------
// K1: xW[t][b][g] = emb[token(t,b)] @ Wih^T + bias  for all 191 steps (fp32 out)
// grid (16, 191): x = 64-col slice, y = timestep. Also zero-inits h buffer +
// barrier words (t==0 blocks), since ws is poisoned before every launch.
// ---------------------------------------------------------------------------
__global__ void __launch_bounds__(256) k_input(
        const int* __restrict__ src, const int* __restrict__ trg,
        const float* __restrict__ emb_src, const float* __restrict__ emb_trg,
        const float* __restrict__ Wih_e, const float* __restrict__ Wih_d,
        const float* __restrict__ b_e, const float* __restrict__ b_d,
        float* __restrict__ xW, unsigned* __restrict__ bar,
        unsigned short* __restrict__ hbuf) {
    const int t = blockIdx.y;
    const int nb = blockIdx.x;
    const int tid = threadIdx.x;
    const bool enc = (t < Ssz);
    const float* emb  = enc ? emb_src : emb_trg;
    const float* Wih  = enc ? Wih_e : Wih_d;
    const float* bias = enc ? b_e : b_d;

    __shared__ unsigned short a_lds[32][Esz + 8];   // [32][136] bf16

    {   // stage embedding rows (bf16) for the 32 batch elements
        int b = tid >> 3, seg = tid & 7;
        int tok = enc ? src[b * Ssz + t] : trg[b * Tsz + (t - Ssz)];
        const float* row = emb + (long)tok * Esz + seg * 16;
        #pragma unroll
        for (int i = 0; i < 16; ++i)
            a_lds[b][seg * 16 + i] = f2bf(row[i]);
    }
    if (t == 0) {
        ((unsigned*)hbuf)[nb * 256 + tid] = 0u;     // zero h double-buffer slot 0 (16 KB)
        if (nb == 0 && tid < 2) bar[tid] = 0u;      // barrier count + generation
    }
    __syncthreads();

    const int w = tid >> 6, l = tid & 63;
    const int n = l & 15, q = l >> 4;
    const int col = nb * 64 + w * 16 + n;           // 0..1023

    short8 bw[4];
    #pragma unroll
    for (int kt = 0; kt < 4; ++kt) {
        const float* wr = Wih + (long)col * Esz + kt * 32 + q * 8;
        short8 f;
        #pragma unroll
        for (int i = 0; i < 8; ++i) f[i] = (short)f2bf(wr[i]);
        bw[kt] = f;
    }
    f32x4 acc0 = {0.f,0.f,0.f,0.f}, acc1 = {0.f,0.f,0.f,0.f};
    #pragma unroll
    for (int kt = 0; kt < 4; ++kt) {
        int k0 = kt * 32 + q * 8;
        short8 a0 = *(const short8*)&a_lds[n][k0];
        short8 a1 = *(const short8*)&a_lds[16 + n][k0];
        acc0 = __builtin_amdgcn_mfma_f32_16x16x32_bf16(a0, bw[kt], acc0, 0, 0, 0);
        acc1 = __builtin_amdgcn_mfma_f32_16x16x32_bf16(a1, bw[kt], acc1, 0, 0, 0);
    }
    float bv = bias[col];
    float* o = xW + (long)t * (Bsz * G4);
    #pragma unroll
    for (int r = 0; r < 4; ++r) {
        int m = q * 4 + r;
        o[m * G4 + col]        = acc0[r] + bv;
        o[(16 + m) * G4 + col] = acc1[r] + bv;
    }
}

// ---------------------------------------------------------------------------
// K2: LSTM recurrence, 191 steps. 16 blocks; block nb owns h columns
// [nb*16, nb*16+16) (all 4 gates for those cols -> pointwise is block-local).
// Whh fragments live in registers (enc + dec). h double-buffered in global.
// Custom device-scope barrier once per step.
// ---------------------------------------------------------------------------
__global__ void __launch_bounds__(256) k_recur(
        const float* __restrict__ Whh_e, const float* __restrict__ Whh_d,
        const float* __restrict__ xW, unsigned short* __restrict__ hbuf,
        unsigned short* __restrict__ hs, float* __restrict__ out_tail,
        unsigned* __restrict__ bar) {
    const int nb = blockIdx.x, tid = threadIdx.x;
    const int w = tid >> 6, l = tid & 63, n = l & 15, q = l >> 4;
    const int jbase = nb * 16;
    const int grow = w * Hsz + jbase + n;           // Whh row (gate w)

    __shared__ unsigned short h_lds[32][Hsz + 8];   // [32][264] bf16
    __shared__ float glds[4][32][17];
    __shared__ float c_lds[32][16];

    short8 be[8], bd[8];
    #pragma unroll
    for (int kt = 0; kt < 8; ++kt) {
        const float* we = Whh_e + (long)grow * Hsz + kt * 32 + q * 8;
        const float* wd = Whh_d + (long)grow * Hsz + kt * 32 + q * 8;
        short8 fe, fd;
        #pragma unroll
        for (int i = 0; i < 8; ++i) { fe[i] = (short)f2bf(we[i]); fd[i] = (short)f2bf(wd[i]); }
        be[kt] = fe; bd[kt] = fd;
    }
    #pragma unroll
    for (int pp = 0; pp < 2; ++pp) {
        int p = tid + pp * 256;
        c_lds[p >> 4][p & 15] = 0.f;
    }

    for (int s = 0; s < NSTEP; ++s) {
        const unsigned short* hsrc = hbuf + (s & 1) * (Bsz * Hsz);
        unsigned short* hdst = hbuf + ((s + 1) & 1) * (Bsz * Hsz);
        {   // stage h -> LDS (16 KB), coalesced
            int b = tid >> 3, seg = tid & 7;
            const uint4* g = (const uint4*)(hsrc + b * Hsz);
            #pragma unroll
            for (int i = 0; i < 4; ++i)
                *(uint4*)&h_lds[b][i * 64 + seg * 8] = g[i * 8 + seg];
        }
        __syncthreads();

        f32x4 acc0 = {0.f,0.f,0.f,0.f}, acc1 = {0.f,0.f,0.f,0.f};
        if (s < Ssz) {
            #pragma unroll
            for (int kt = 0; kt < 8; ++kt) {
                int k0 = kt * 32 + q * 8;
                short8 a0 = *(const short8*)&h_lds[n][k0];
                short8 a1 = *(const short8*)&h_lds[16 + n][k0];
                acc0 = __builtin_amdgcn_mfma_f32_16x16x32_bf16(a0, be[kt], acc0, 0, 0, 0);
                acc1 = __builtin_amdgcn_mfma_f32_16x16x32_bf16(a1, be[kt], acc1, 0, 0, 0);
            }
        } else {
            #pragma unroll
            for (int kt = 0; kt < 8; ++kt) {
                int k0 = kt * 32 + q * 8;
                short8 a0 = *(const short8*)&h_lds[n][k0];
                short8 a1 = *(const short8*)&h_lds[16 + n][k0];
                acc0 = __builtin_amdgcn_mfma_f32_16x16x32_bf16(a0, bd[kt], acc0, 0, 0, 0);
                acc1 = __builtin_amdgcn_mfma_f32_16x16x32_bf16(a1, bd[kt], acc1, 0, 0, 0);
            }
        }
        #pragma unroll
        for (int r = 0; r < 4; ++r) {
            glds[w][q * 4 + r][n]      = acc0[r];
            glds[w][16 + q * 4 + r][n] = acc1[r];
        }
        __syncthreads();

        const float* xrow = xW + (long)s * (Bsz * G4);
        #pragma unroll
        for (int pp = 0; pp < 2; ++pp) {
            int p = tid + pp * 256;
            int b = p >> 4, j = p & 15;
            int jc = jbase + j;
            float gi = glds[0][b][j] + xrow[b * G4 + 0 * Hsz + jc];
            float gf = glds[1][b][j] + xrow[b * G4 + 1 * Hsz + jc];
            float gg = glds[2][b][j] + xrow[b * G4 + 2 * Hsz + jc];
            float go = glds[3][b][j] + xrow[b * G4 + 3 * Hsz + jc];
            float c = c_lds[b][j];
            c = sigm(gf) * c + sigm(gi) * tanhf(gg);
            c_lds[b][j] = c;
            float h = sigm(go) * tanhf(c);
            hdst[b * Hsz + jc] = f2bf(h);
            if (s >= Ssz) hs[((long)(s - Ssz) * Bsz + b) * Hsz + jc] = f2bf(h);
            if (s == NSTEP - 1) {
                out_tail[b * Hsz + jc] = h;                // hn (fp32)
                out_tail[Bsz * Hsz + b * Hsz + jc] = c;    // cn (fp32)
            }
        }

        __syncthreads();   // all LDS reads + global h stores done (waitcnt before barrier)
        if (tid == 0) {
            __threadfence();                              // release my h stores device-wide
            unsigned old = atomicAdd(bar, 1u);
            if (old == NB - 1) {
                __hip_atomic_store(bar, 0u, __ATOMIC_RELAXED, __HIP_MEMORY_SCOPE_AGENT);
                __hip_atomic_store(bar + 1, (unsigned)(s + 1), __ATOMIC_RELEASE, __HIP_MEMORY_SCOPE_AGENT);
            } else {
                while (__hip_atomic_load(bar + 1, __ATOMIC_ACQUIRE, __HIP_MEMORY_SCOPE_AGENT)
                       != (unsigned)(s + 1)) {
                    __builtin_amdgcn_s_sleep(1);
                }
            }
            __threadfence();                              // acquire: invalidate stale caches
        }
        __syncthreads();
    }
}

// ---------------------------------------------------------------------------
// K3: projection out[b][td+1][v] = hs[td][b][:] @ Wfc[v][:] + bfc[v]
// grid (125, 63): x = 256-col slice of V, y = decoder step. bf16 MFMA.
// ---------------------------------------------------------------------------
__global__ void __launch_bounds__(256) k_proj(
        const unsigned short* __restrict__ hs, const unsigned short* __restrict__ WfcB,
        const float* __restrict__ bfc, float* __restrict__ out) {
    const int vb = blockIdx.x;    // 0..124
    const int td = blockIdx.y;    // 0..62
    const int tid = threadIdx.x, w = tid >> 6, l = tid & 63, n = l & 15, q = l >> 4;

    __shared__ unsigned short a_lds[32][Hsz + 8];     // 16.5 KB
    __shared__ unsigned short b_lds[256][Hsz + 8];    // 132 KB

    {   // stage A: hs rows for this td (contiguous 16 KB)
        int b = tid >> 3, seg = tid & 7;
        const uint4* g = (const uint4*)(hs + ((long)td * Bsz + b) * Hsz);
        #pragma unroll
        for (int i = 0; i < 4; ++i)
            *(uint4*)&a_lds[b][i * 64 + seg * 8] = g[i * 8 + seg];
    }
    {   // stage B tile: 128 KB contiguous from WfcB, remapped into padded rows
        const uint4* g = (const uint4*)(WfcB + (long)vb * 256 * Hsz);
        #pragma unroll 4
        for (int i = 0; i < 32; ++i) {
            int u = i * 256 + tid;           // uint4 index (8 bf16 each)
            int row = u >> 5;
            int kk = (u & 31) * 8;
            *(uint4*)&b_lds[row][kk] = g[u];
        }
    }
    __syncthreads();

    short8 af[2][8];
    #pragma unroll
    for (int kt = 0; kt < 8; ++kt) {
        int k0 = kt * 32 + q * 8;
        af[0][kt] = *(const short8*)&a_lds[n][k0];
        af[1][kt] = *(const short8*)&a_lds[16 + n][k0];
    }
    f32x4 acc[2][4];
    #pragma unroll
    for (int nt = 0; nt < 4; ++nt) { acc[0][nt] = (f32x4){0.f,0.f,0.f,0.f}; acc[1][nt] = (f32x4){0.f,0.f,0.f,0.f}; }

    #pragma unroll
    for (int nt = 0; nt < 4; ++nt) {
        int cl = w * 64 + nt * 16 + n;
        #pragma unroll
        for (int kt = 0; kt < 8; ++kt) {
            short8 bf = *(const short8*)&b_lds[cl][kt * 32 + q * 8];
            acc[0][nt] = __builtin_amdgcn_mfma_f32_16x16x32_bf16(af[0][kt], bf, acc[0][nt], 0, 0, 0);
            acc[1][nt] = __builtin_amdgcn_mfma_f32_16x16x32_bf16(af[1][kt], bf, acc[1][nt], 0, 0, 0);
        }
    }
    #pragma unroll
    for (int nt = 0; nt < 4; ++nt) {
        int col = vb * 256 + w * 64 + nt * 16 + n;
        float bv = bfc[col];
        #pragma unroll
        for (int mt = 0; mt < 2; ++mt) {
            #pragma unroll
            for (int r = 0; r < 4; ++r) {
                int b = mt * 16 + q * 4 + r;
                out[(long)b * (Tsz * Vsz) + (long)(td + 1) * Vsz + col] = acc[mt][nt][r] + bv;
            }
        }
    }
}

// ---------------------------------------------------------------------------
// K4: zero prediction slot t=0 (d_out is poisoned before every launch)
// ---------------------------------------------------------------------------
__global__ void k_zero0(float* __restrict__ out) {
    int i = blockIdx.x * 256 + threadIdx.x;    // 256000 float4s = 32*32000 floats
    int b = i / 8000;
    int c = i % 8000;
    ((float4*)(out + (long)b * (Tsz * Vsz)))[c] = make_float4(0.f, 0.f, 0.f, 0.f);
}

// ---------------------------------------------------------------------------
extern "C" void kernel_launch(void* const* d_in, const int* in_sizes, int n_in,
                              void* d_out, int out_size, void* d_ws, size_t ws_size,
                              hipStream_t stream) {
    const int*   src     = (const int*)d_in[0];
    const int*   trg     = (const int*)d_in[1];
    const float* emb_src = (const float*)d_in[2];
    const float* Wih_e   = (const float*)d_in[3];
    const float* Whh_e   = (const float*)d_in[4];
    const float* b_e     = (const float*)d_in[5];
    const float* emb_trg = (const float*)d_in[6];
    const float* Wih_d   = (const float*)d_in[7];
    const float* Whh_d   = (const float*)d_in[8];
    const float* b_d     = (const float*)d_in[9];
    const float* Wfc     = (const float*)d_in[10];
    const float* bfc     = (const float*)d_in[11];
    float* out = (float*)d_out;

    char* ws = (char*)d_ws;
    float*          xW   = (float*)ws;                          // 191*32*1024*4 = 25,034,752 B
    unsigned short* WfcB = (unsigned short*)(ws + 25034752);    // 32000*256*2  = 16,384,000 B
    unsigned short* hs   = (unsigned short*)(ws + 41418752);    // 63*32*256*2  =  1,032,192 B
    unsigned short* hbuf = (unsigned short*)(ws + 42450944);    // 2*32*256*2   =     32,768 B
    unsigned*       bar  = (unsigned*)(ws + 42483712);          // 8 B

    k_cvt<<<4000, 256, 0, stream>>>(Wfc, WfcB, 8192000L);
    k_input<<<dim3(16, 191), 256, 0, stream>>>(src, trg, emb_src, emb_trg,
                                               Wih_e, Wih_d, b_e, b_d, xW, bar, hbuf);
    k_recur<<<NB, 256, 0, stream>>>(Whh_e, Whh_d, xW, hbuf, hs, out + 65536000L, bar);
    k_zero0<<<1000, 256, 0, stream>>>(out);
    k_proj<<<dim3(125, 63), 256, 0, stream>>>(hs, WfcB, bfc, out);
}

// Round 4
// 1159.608 us; speedup vs baseline: 1.1971x; 1.1971x over previous
//
#include <hip/hip_runtime.h>
#include <hip/hip_bf16.h>

#define Bsz 32
#define Ssz 128
#define Tsz 64
#define TD  63           // decoder steps
#define NSTEP 191        // Ssz + TD
#define Esz 128
#define Hsz 256
#define G4  1024         // 4*H
#define Vsz 32000
#define NB  16           // recurrence blocks

typedef __attribute__((ext_vector_type(8))) short short8;
typedef __attribute__((ext_vector_type(4))) float f32x4;

__device__ __forceinline__ unsigned short f2bf(float f) {
    union { float f; unsigned u; } v; v.f = f;
    unsigned u = v.u;
    unsigned r = u + 0x7FFFu + ((u >> 16) & 1u);   // RNE
    return (unsigned short)(r >> 16);
}

__device__ __forceinline__ float rcpf(float x) { return __builtin_amdgcn_rcpf(x); }
__device__ __forceinline__ float sigm(float x) { return rcpf(1.f + __expf(-x)); }
// tanh(x) = 1 - 2/(e^{2x}+1); saturates correctly at +-inf
__device__ __forceinline__ float tanh_fast(float x) { return 1.f - 2.f * rcpf(1.f + __expf(2.f * x)); }

// ---------------------------------------------------------------------------
// K0: convert Wfc fp32 -> bf16 in workspace
// ---------------------------------------------------------------------------
__global__ void k_cvt(const float* __restrict__ src, unsigned short* __restrict__ dst, long n) {
    long i = (long)blockIdx.x * blockDim.x + threadIdx.x;
    long base = i * 8;
    if (base >= n) return;
    float4 f0 = ((const float4*)(src + base))[0];
    float4 f1 = ((const float4*)(src + base))[1];
    union { unsigned short u[8]; uint4 v; } r;
    r.u[0] = f2bf(f0.x); r.u[1] = f2bf(f0.y); r.u[2] = f2bf(f0.z); r.u[3] = f2bf(f0.w);
    r.u[4] = f2bf(f1.x); r.u[5] = f2bf(f1.y); r.u[6] = f2bf(f1.z); r.u[7] = f2bf(f1.w);
    *(uint4*)(dst + base) = r.v;
}

// ---------------------------------------------------------------------------
// K1: xW[t][b][g] = emb[token(t,b)] @ Wih^T + bias  for all 191 steps (fp32 out)
// grid (16, 191). Also zero-inits h buffer slot 0 + barrier flags (t==0),
// using agent-scope atomic stores so k_recur's L3-bypassing loads see them.
// ---------------------------------------------------------------------------
__global__ void __launch_bounds__(256) k_input(
        const int* __restrict__ src, const int* __restrict__ trg,
        const float* __restrict__ emb_src, const float* __restrict__ emb_trg,
        const float* __restrict__ Wih_e, const float* __restrict__ Wih_d,
        const float* __restrict__ b_e, const float* __restrict__ b_d,
        float* __restrict__ xW, unsigned* __restrict__ bar,
        unsigned* __restrict__ hbuf_dw) {
    const int t = blockIdx.y;
    const int nb = blockIdx.x;
    const int tid = threadIdx.x;
    const bool enc = (t < Ssz);
    const float* emb  = enc ? emb_src : emb_trg;
    const float* Wih  = enc ? Wih_e : Wih_d;
    const float* bias = enc ? b_e : b_d;

    __shared__ unsigned short a_lds[32][Esz + 8];   // [32][136] bf16

    {   // stage embedding rows (bf16) for the 32 batch elements
        int b = tid >> 3, seg = tid & 7;
        int tok = enc ? src[b * Ssz + t] : trg[b * Tsz + (t - Ssz)];
        const float* row = emb + (long)tok * Esz + seg * 16;
        #pragma unroll
        for (int i = 0; i < 16; ++i)
            a_lds[b][seg * 16 + i] = f2bf(row[i]);
    }
    if (t == 0) {
        // slot 0 of hbuf = 4096 dwords; 16 blocks x 256 threads covers it
        __hip_atomic_store(&hbuf_dw[nb * 256 + tid], 0u, __ATOMIC_RELAXED,
                           __HIP_MEMORY_SCOPE_AGENT);
        if (nb == 0) {      // 512 dwords of flag space
            __hip_atomic_store(&bar[tid], 0u, __ATOMIC_RELAXED, __HIP_MEMORY_SCOPE_AGENT);
            __hip_atomic_store(&bar[256 + tid], 0u, __ATOMIC_RELAXED, __HIP_MEMORY_SCOPE_AGENT);
        }
    }
    __syncthreads();

    const int w = tid >> 6, l = tid & 63;
    const int n = l & 15, q = l >> 4;
    const int col = nb * 64 + w * 16 + n;           // 0..1023

    short8 bw[4];
    #pragma unroll
    for (int kt = 0; kt < 4; ++kt) {
        const float* wr = Wih + (long)col * Esz + kt * 32 + q * 8;
        short8 f;
        #pragma unroll
        for (int i = 0; i < 8; ++i) f[i] = (short)f2bf(wr[i]);
        bw[kt] = f;
    }
    f32x4 acc0 = {0.f,0.f,0.f,0.f}, acc1 = {0.f,0.f,0.f,0.f};
    #pragma unroll
    for (int kt = 0; kt < 4; ++kt) {
        int k0 = kt * 32 + q * 8;
        short8 a0 = *(const short8*)&a_lds[n][k0];
        short8 a1 = *(const short8*)&a_lds[16 + n][k0];
        acc0 = __builtin_amdgcn_mfma_f32_16x16x32_bf16(a0, bw[kt], acc0, 0, 0, 0);
        acc1 = __builtin_amdgcn_mfma_f32_16x16x32_bf16(a1, bw[kt], acc1, 0, 0, 0);
    }
    float bv = bias[col];
    float* o = xW + (long)t * (Bsz * G4);
    #pragma unroll
    for (int r = 0; r < 4; ++r) {
        int m = q * 4 + r;
        o[m * G4 + col]        = acc0[r] + bv;
        o[(16 + m) * G4 + col] = acc1[r] + bv;
    }
}

// ---------------------------------------------------------------------------
// K2: LSTM recurrence, 191 steps, 16 blocks. h exchanged through L3 via
// relaxed agent-scope (cache-bypassing) atomics -> NO threadfence, L2 stays
// warm for xW. Barrier = flag-per-block broadcast: __syncthreads() drains
// vmcnt(0) (h stores acked at L3), tid0 relaxed-stores flag[nb]=s+1, next
// step 16 lanes of wave0 spin one flag each. c state lives in VGPRs.
// Round-2 bug history: (a) slot stride was half-size -> overlap race (fixed
// r3: 4096 dw / 2048 u64 per slot); (b) stage-C loop was i<4 -> only HALF of
// h staged, LDS rows 16..31 never written (fixed here: i<8 = 2048 u64 = 16KB).
// ---------------------------------------------------------------------------
__global__ void __launch_bounds__(256) k_recur(
        const float* __restrict__ Whh_e, const float* __restrict__ Whh_d,
        const float* __restrict__ xW, unsigned* __restrict__ hbuf_dw,
        unsigned* __restrict__ hs_dw, float* __restrict__ out_tail,
        unsigned* __restrict__ bar) {
    const int nb = blockIdx.x, tid = threadIdx.x;
    const int w = tid >> 6, l = tid & 63, n = l & 15, q = l >> 4;
    const int jbase = nb * 16;
    const int grow = w * Hsz + jbase + n;           // Whh row (gate w)

    __shared__ unsigned short h_lds[32][Hsz + 8];   // [32][264] bf16
    __shared__ float glds[4][32][17];

    short8 be[8], bd[8];
    #pragma unroll
    for (int kt = 0; kt < 8; ++kt) {
        const float* we = Whh_e + (long)grow * Hsz + kt * 32 + q * 8;
        const float* wd = Whh_d + (long)grow * Hsz + kt * 32 + q * 8;
        short8 fe, fd;
        #pragma unroll
        for (int i = 0; i < 8; ++i) { fe[i] = (short)f2bf(we[i]); fd[i] = (short)f2bf(wd[i]); }
        be[kt] = fe; bd[kt] = fd;
    }

    // pointwise mapping: thread handles (batch pb, cols j0,j0+1)
    const int pb = tid >> 3, jp = tid & 7, j0 = 2 * jp;
    float c0 = 0.f, c1 = 0.f;

    for (int s = 0; s < NSTEP; ++s) {
        // A: preload this thread's x-gate values (independent of h -> hides
        //    L2/L3 latency behind the barrier spin)
        const float* xrow = xW + (long)s * (Bsz * G4) + pb * G4 + jbase + j0;
        float2 xg0 = *(const float2*)(xrow + 0 * Hsz);
        float2 xg1 = *(const float2*)(xrow + 1 * Hsz);
        float2 xg2 = *(const float2*)(xrow + 2 * Hsz);
        float2 xg3 = *(const float2*)(xrow + 3 * Hsz);

        // B: wait until every block published step s-1's h (flags >= s)
        if (tid < NB) {
            while (__hip_atomic_load(&bar[tid * 32], __ATOMIC_RELAXED,
                                     __HIP_MEMORY_SCOPE_AGENT) < (unsigned)s) {}
        }
        __syncthreads();

        // C: stage h (slot s&1) -> LDS via L3-bypass u64 atomic loads.
        //    FULL h = 2048 u64 (16 KB) -> 8 iterations x 256 threads.
        {
            const unsigned long long* hsrc =
                (const unsigned long long*)hbuf_dw + (s & 1) * 2048;   // slot = 2048 u64
            #pragma unroll
            for (int i = 0; i < 8; ++i) {
                int d2 = i * 256 + tid;              // u64 index, 4 bf16 each
                unsigned long long v = __hip_atomic_load(hsrc + d2, __ATOMIC_RELAXED,
                                                         __HIP_MEMORY_SCOPE_AGENT);
                int b = d2 >> 6, cq = d2 & 63;       // 64 u64 per h row
                *(unsigned long long*)((char*)&h_lds[0][0] + b * 528 + cq * 8) = v;
            }
        }
        __syncthreads();

        // D: MFMA (Whh in registers)
        f32x4 acc0 = {0.f,0.f,0.f,0.f}, acc1 = {0.f,0.f,0.f,0.f};
        if (s < Ssz) {
            #pragma unroll
            for (int kt = 0; kt < 8; ++kt) {
                int k0 = kt * 32 + q * 8;
                short8 a0 = *(const short8*)&h_lds[n][k0];
                short8 a1 = *(const short8*)&h_lds[16 + n][k0];
                acc0 = __builtin_amdgcn_mfma_f32_16x16x32_bf16(a0, be[kt], acc0, 0, 0, 0);
                acc1 = __builtin_amdgcn_mfma_f32_16x16x32_bf16(a1, be[kt], acc1, 0, 0, 0);
            }
        } else {
            #pragma unroll
            for (int kt = 0; kt < 8; ++kt) {
                int k0 = kt * 32 + q * 8;
                short8 a0 = *(const short8*)&h_lds[n][k0];
                short8 a1 = *(const short8*)&h_lds[16 + n][k0];
                acc0 = __builtin_amdgcn_mfma_f32_16x16x32_bf16(a0, bd[kt], acc0, 0, 0, 0);
                acc1 = __builtin_amdgcn_mfma_f32_16x16x32_bf16(a1, bd[kt], acc1, 0, 0, 0);
            }
        }
        #pragma unroll
        for (int r = 0; r < 4; ++r) {
            glds[w][q * 4 + r][n]      = acc0[r];
            glds[w][16 + q * 4 + r][n] = acc1[r];
        }
        __syncthreads();

        // E: pointwise LSTM for (pb, j0) and (pb, j0+1)
        float gi0 = glds[0][pb][j0] + xg0.x, gi1 = glds[0][pb][j0 + 1] + xg0.y;
        float gf0 = glds[1][pb][j0] + xg1.x, gf1 = glds[1][pb][j0 + 1] + xg1.y;
        float gg0 = glds[2][pb][j0] + xg2.x, gg1 = glds[2][pb][j0 + 1] + xg2.y;
        float go0 = glds[3][pb][j0] + xg3.x, go1 = glds[3][pb][j0 + 1] + xg3.y;
        c0 = sigm(gf0) * c0 + sigm(gi0) * tanh_fast(gg0);
        c1 = sigm(gf1) * c1 + sigm(gi1) * tanh_fast(gg1);
        float h0 = sigm(go0) * tanh_fast(c0);
        float h1 = sigm(go1) * tanh_fast(c1);

        unsigned pk = (unsigned)f2bf(h0) | ((unsigned)f2bf(h1) << 16);
        unsigned* hdst = hbuf_dw + ((s + 1) & 1) * 4096            // slot = 4096 dwords
                         + pb * 128 + (jbase >> 1) + jp;
        __hip_atomic_store(hdst, pk, __ATOMIC_RELAXED, __HIP_MEMORY_SCOPE_AGENT);
        if (s >= Ssz)
            hs_dw[((long)(s - Ssz) * Bsz + pb) * 128 + (jbase >> 1) + jp] = pk;
        if (s == NSTEP - 1) {
            int jc = jbase + j0;
            *(float2*)&out_tail[pb * Hsz + jc]             = make_float2(h0, h1);
            *(float2*)&out_tail[Bsz * Hsz + pb * Hsz + jc] = make_float2(c0, c1);
        }

        // F: __syncthreads drains vmcnt(0) in every wave -> all h stores are
        //    acked at the L3 coherence point; then publish the flag.
        __syncthreads();
        if (tid == 0)
            __hip_atomic_store(&bar[nb * 32], (unsigned)(s + 1), __ATOMIC_RELAXED,
                               __HIP_MEMORY_SCOPE_AGENT);
    }
}

// ---------------------------------------------------------------------------
// K3: projection out[b][td+1][v] = hs[td][b][:] @ Wfc[v][:] + bfc[v]
// grid (125, 63): x = 256-col slice of V, y = decoder step. bf16 MFMA.
// ---------------------------------------------------------------------------
__global__ void __launch_bounds__(256) k_proj(
        const unsigned short* __restrict__ hs, const unsigned short* __restrict__ WfcB,
        const float* __restrict__ bfc, float* __restrict__ out) {
    const int vb = blockIdx.x;    // 0..124
    const int td = blockIdx.y;    // 0..62
    const int tid = threadIdx.x, w = tid >> 6, l = tid & 63, n = l & 15, q = l >> 4;

    __shared__ unsigned short a_lds[32][Hsz + 8];     // 16.5 KB
    __shared__ unsigned short b_lds[256][Hsz + 8];    // 132 KB

    {   // stage A: hs rows for this td (contiguous 16 KB)
        int b = tid >> 3, seg = tid & 7;
        const uint4* g = (const uint4*)(hs + ((long)td * Bsz + b) * Hsz);
        #pragma unroll
        for (int i = 0; i < 4; ++i)
            *(uint4*)&a_lds[b][i * 64 + seg * 8] = g[i * 8 + seg];
    }
    {   // stage B tile: 128 KB contiguous from WfcB, remapped into padded rows
        const uint4* g = (const uint4*)(WfcB + (long)vb * 256 * Hsz);
        #pragma unroll 4
        for (int i = 0; i < 32; ++i) {
            int u = i * 256 + tid;           // uint4 index (8 bf16 each)
            int row = u >> 5;
            int kk = (u & 31) * 8;
            *(uint4*)&b_lds[row][kk] = g[u];
        }
    }
    __syncthreads();

    short8 af[2][8];
    #pragma unroll
    for (int kt = 0; kt < 8; ++kt) {
        int k0 = kt * 32 + q * 8;
        af[0][kt] = *(const short8*)&a_lds[n][k0];
        af[1][kt] = *(const short8*)&a_lds[16 + n][k0];
    }
    f32x4 acc[2][4];
    #pragma unroll
    for (int nt = 0; nt < 4; ++nt) { acc[0][nt] = (f32x4){0.f,0.f,0.f,0.f}; acc[1][nt] = (f32x4){0.f,0.f,0.f,0.f}; }

    #pragma unroll
    for (int nt = 0; nt < 4; ++nt) {
        int cl = w * 64 + nt * 16 + n;
        #pragma unroll
        for (int kt = 0; kt < 8; ++kt) {
            short8 bf = *(const short8*)&b_lds[cl][kt * 32 + q * 8];
            acc[0][nt] = __builtin_amdgcn_mfma_f32_16x16x32_bf16(af[0][kt], bf, acc[0][nt], 0, 0, 0);
            acc[1][nt] = __builtin_amdgcn_mfma_f32_16x16x32_bf16(af[1][kt], bf, acc[1][nt], 0, 0, 0);
        }
    }
    #pragma unroll
    for (int nt = 0; nt < 4; ++nt) {
        int col = vb * 256 + w * 64 + nt * 16 + n;
        float bv = bfc[col];
        #pragma unroll
        for (int mt = 0; mt < 2; ++mt) {
            #pragma unroll
            for (int r = 0; r < 4; ++r) {
                int b = mt * 16 + q * 4 + r;
                out[(long)b * (Tsz * Vsz) + (long)(td + 1) * Vsz + col] = acc[mt][nt][r] + bv;
            }
        }
    }
}

// ---------------------------------------------------------------------------
// K4: zero prediction slot t=0 (d_out is poisoned before every launch)
// ---------------------------------------------------------------------------
__global__ void k_zero0(float* __restrict__ out) {
    int i = blockIdx.x * 256 + threadIdx.x;    // 256000 float4s = 32*32000 floats
    int b = i / 8000;
    int c = i % 8000;
    ((float4*)(out + (long)b * (Tsz * Vsz)))[c] = make_float4(0.f, 0.f, 0.f, 0.f);
}

// ---------------------------------------------------------------------------
extern "C" void kernel_launch(void* const* d_in, const int* in_sizes, int n_in,
                              void* d_out, int out_size, void* d_ws, size_t ws_size,
                              hipStream_t stream) {
    const int*   src     = (const int*)d_in[0];
    const int*   trg     = (const int*)d_in[1];
    const float* emb_src = (const float*)d_in[2];
    const float* Wih_e   = (const float*)d_in[3];
    const float* Whh_e   = (const float*)d_in[4];
    const float* b_e     = (const float*)d_in[5];
    const float* emb_trg = (const float*)d_in[6];
    const float* Wih_d   = (const float*)d_in[7];
    const float* Whh_d   = (const float*)d_in[8];
    const float* b_d     = (const float*)d_in[9];
    const float* Wfc     = (const float*)d_in[10];
    const float* bfc     = (const float*)d_in[11];
    float* out = (float*)d_out;

    char* ws = (char*)d_ws;
    float*          xW   = (float*)ws;                          // 191*32*1024*4 = 25,034,752 B
    unsigned short* WfcB = (unsigned short*)(ws + 25034752);    // 32000*256*2  = 16,384,000 B
    unsigned short* hs   = (unsigned short*)(ws + 41418752);    // 63*32*256*2  =  1,032,192 B
    unsigned*       hbuf = (unsigned*)(ws + 42450944);          // 2 slots x 16 KB = 32,768 B
    unsigned*       bar  = (unsigned*)(ws + 42483712);          // 16 flags @ 128 B stride = 2048 B
    (void)ws_size;

    k_cvt<<<4000, 256, 0, stream>>>(Wfc, WfcB, 8192000L);
    k_input<<<dim3(16, 191), 256, 0, stream>>>(src, trg, emb_src, emb_trg,
                                               Wih_e, Wih_d, b_e, b_d, xW, bar, hbuf);
    k_recur<<<NB, 256, 0, stream>>>(Whh_e, Whh_d, xW, hbuf, (unsigned*)hs,
                                    out + 65536000L, bar);
    k_zero0<<<1000, 256, 0, stream>>>(out);
    k_proj<<<dim3(125, 63), 256, 0, stream>>>(hs, WfcB, bfc, out);
}